// Round 7
// baseline (656.356 us; speedup 1.0000x reference)
//
#include <hip/hip_runtime.h>

// Native clang vector type — accepted by __builtin_nontemporal_load/store
typedef float vf4 __attribute__((ext_vector_type(4)));

// Workspace float offsets
#define WS_FPART 0      // fpart[4][128]
#define WS_H2    512    // h2[450]

// K1: fpart[t][i] = sum_{p,c} x[4+t,p,c] * TwE[t,i] * PE[p,i] * CE[c,i]
// 512 blocks = 4 per output i (one per t). Per-block L2-broadcast read = 128 KB.
__global__ __launch_bounds__(256) void k_f(
    const float* __restrict__ x, const float* __restrict__ TwE,
    const float* __restrict__ PE, const float* __restrict__ CE,
    float* __restrict__ fpart) {
  const int i = blockIdx.x >> 2;
  const int t = blockIdx.x & 3;
  const int tid = threadIdx.x;
  __shared__ float sCE[128];
  __shared__ float coef[256];   // coef[p] = TwE[t,i] * PE[p,i]
  __shared__ float red[4];
  const float tw = TwE[t * 128 + i];     // wave-uniform scalar load
  if (tid < 128) sCE[tid] = CE[tid * 128 + i];
  coef[tid] = tw * PE[tid * 128 + i];
  __syncthreads();
  const int lane = tid & 63;
  const int wv = tid >> 6;
  const float2 ce = ((const float2*)sCE)[lane];
  const float2* Xw = (const float2*)(x + 4 * 256 * 128);  // window start
  float acc = 0.f;
  const int l0 = wv * 64;                // each wave: 64 of this block's 256 p-rows
#pragma unroll 8
  for (int k = 0; k < 64; ++k) {
    int l = l0 + k;                      // p index
    int q = (t << 8) + l;                // global (t,p) row in window
    float2 v = Xw[q * 64 + lane];        // coalesced 512B wave load
    acc += coef[l] * (v.x * ce.x + v.y * ce.y);
  }
#pragma unroll
  for (int off = 32; off > 0; off >>= 1) acc += __shfl_down(acc, off);
  if (lane == 0) red[wv] = acc;
  __syncthreads();
  if (tid == 0) fpart[t * 128 + i] = red[0] + red[1] + red[2] + red[3];
}

// K2: fused middle chain via redundant compute, WAVE-PER-ROW everywhere.
// Round-5 post-mortem: thread-per-row streaming of 1800B rows made every
// wave-load touch 64 distinct cache lines (~64 L1 line-transactions per load,
// ~96 us across the two 450x450 phases). Wave-per-row restores lane-contiguous
// loads (8 lines per wave-load). Each of 113 blocks redundantly computes
// feat0/h1/feat for ALL 450 rows (4 waves x 113 rows), then its own 4 h2 rows.
__global__ __launch_bounds__(256) void k_rest(
    const float* __restrict__ fpart, const float* __restrict__ mE,
    const float* __restrict__ eW1, const float* __restrict__ eb1,
    const float* __restrict__ eW2, const float* __restrict__ eb2,
    const float* __restrict__ dW1, const float* __restrict__ db1,
    float* __restrict__ h2) {
  __shared__ float sf[128];
  __shared__ float sfeat0[450];
  __shared__ float sh1[450];
  __shared__ float sfeat[450];
  const int tid  = threadIdx.x;
  const int lane = tid & 63;
  const int wv   = tid >> 6;
  if (tid < 128)
    sf[tid] = (fpart[tid] + fpart[128 + tid]) + (fpart[256 + tid] + fpart[384 + tid]);
  __syncthreads();

  // feat0 = mE @ sf — wave per row: 128 floats = exactly 64 float2, one per lane.
  for (int r = wv; r < 450; r += 4) {
    const float2 m = ((const float2*)(mE + r * 128))[lane];   // 512B coalesced
    float a = m.x * sf[2 * lane] + m.y * sf[2 * lane + 1];
#pragma unroll
    for (int off = 32; off > 0; off >>= 1) a += __shfl_down(a, off);
    if (lane == 0) sfeat0[r] = a;
  }
  __syncthreads();

  // h1 = relu(eW1 @ feat0 + eb1) — wave per row, all 450 rows (redundant).
  for (int r = wv; r < 450; r += 4) {
    const float2* row = (const float2*)(eW1 + r * 450);
    float a = 0.f;
#pragma unroll
    for (int k = 0; k < 4; ++k) {
      int idx = lane + (k << 6);
      if (idx < 225) {
        float2 w = row[idx];                       // lane-contiguous
        a += w.x * sfeat0[2 * idx] + w.y * sfeat0[2 * idx + 1];
      }
    }
#pragma unroll
    for (int off = 32; off > 0; off >>= 1) a += __shfl_down(a, off);
    if (lane == 0) sh1[r] = fmaxf(a + eb1[r], 0.f);
  }
  __syncthreads();

  // feat = eW2 @ h1 + eb2 — wave per row, all 450 rows (redundant).
  for (int r = wv; r < 450; r += 4) {
    const float2* row = (const float2*)(eW2 + r * 450);
    float a = 0.f;
#pragma unroll
    for (int k = 0; k < 4; ++k) {
      int idx = lane + (k << 6);
      if (idx < 225) {
        float2 w = row[idx];
        a += w.x * sh1[2 * idx] + w.y * sh1[2 * idx + 1];
      }
    }
#pragma unroll
    for (int off = 32; off > 0; off >>= 1) a += __shfl_down(a, off);
    if (lane == 0) sfeat[r] = a + eb2[r];
  }
  __syncthreads();

  // h2: own 4 rows only, wave per row (same as old k_mv450).
  const int row = blockIdx.x * 4 + wv;
  if (row < 450) {
    const float2* Wr = (const float2*)(dW1 + row * 450);
    float acc = 0.f;
#pragma unroll
    for (int k = 0; k < 4; ++k) {
      int idx = lane + (k << 6);
      if (idx < 225) {
        float2 w = Wr[idx];
        acc += w.x * sfeat[2 * idx] + w.y * sfeat[2 * idx + 1];
      }
    }
#pragma unroll
    for (int off = 32; off > 0; off >>= 1) acc += __shfl_down(acc, off);
    if (lane == 0) h2[row] = fmaxf(acc + db1[row], 0.f);
  }
}

// K3: out = dec_W2 @ h2 + dec_b2. Wave per ROW-PAIR (225 float4, 16B-aligned:
// pair stride 3600B). NT loads/stores (the 900-MiB poison fills flush the LLC
// every replay, so dec_W2 can never be retained — stream it). Round-0-identical.
__global__ __launch_bounds__(512) void k_dec2(
    const float* __restrict__ W, const float* __restrict__ b,
    const float* __restrict__ h, float* __restrict__ out) {
  __shared__ float sv2[900];
  const int tid = threadIdx.x;
  for (int k = tid; k < 900; k += 512) sv2[k] = h[k < 450 ? k : k - 450];
  __syncthreads();
  const int lane = tid & 63;
  const int rp = blockIdx.x * 8 + (tid >> 6);    // row pair, 0..65535
  const vf4* Wp = (const vf4*)(W + (size_t)rp * 900);
  float accA = 0.f, accB = 0.f;
#pragma unroll
  for (int k = 0; k < 3; ++k) {
    int j = lane + (k << 6);          // 0..191
    vf4 w = __builtin_nontemporal_load(&Wp[j]);
    const float* s = &sv2[4 * j];
    float p01 = w.x * s[0] + w.y * s[1];
    float p23 = w.z * s[2] + w.w * s[3];
    if (4 * j + 3 < 450)      accA += p01 + p23;   // j <= 111
    else if (4 * j >= 450)    accB += p01 + p23;   // j >= 113
    else { accA += p01; accB += p23; }             // j == 112 straddles
  }
  if (lane < 33) {                    // j = 192..224, all row B
    int j = 192 + lane;
    vf4 w = __builtin_nontemporal_load(&Wp[j]);
    const float* s = &sv2[4 * j];
    accB += w.x * s[0] + w.y * s[1] + w.z * s[2] + w.w * s[3];
  }
#pragma unroll
  for (int off = 32; off > 0; off >>= 1) {
    accA += __shfl_down(accA, off);
    accB += __shfl_down(accB, off);
  }
  if (lane == 0) {
    int r = rp * 2;
    __builtin_nontemporal_store(accA + b[r],     &out[r]);
    __builtin_nontemporal_store(accB + b[r + 1], &out[r + 1]);
  }
}

extern "C" void kernel_launch(void* const* d_in, const int* in_sizes, int n_in,
                              void* d_out, int out_size, void* d_ws, size_t ws_size,
                              hipStream_t stream) {
  const float* x   = (const float*)d_in[0];
  const float* TwE = (const float*)d_in[2];
  const float* PE  = (const float*)d_in[3];
  const float* CE  = (const float*)d_in[4];
  const float* mE  = (const float*)d_in[5];
  const float* eW1 = (const float*)d_in[6];
  const float* eb1 = (const float*)d_in[7];
  const float* eW2 = (const float*)d_in[8];
  const float* eb2 = (const float*)d_in[9];
  const float* dW1 = (const float*)d_in[10];
  const float* db1 = (const float*)d_in[11];
  const float* dW2 = (const float*)d_in[12];
  const float* db2 = (const float*)d_in[13];
  float* out = (float*)d_out;
  float* ws  = (float*)d_ws;

  k_f   <<<512,  256, 0, stream>>>(x, TwE, PE, CE, ws + WS_FPART);
  k_rest<<<113,  256, 0, stream>>>(ws + WS_FPART, mE, eW1, eb1, eW2, eb2,
                                   dW1, db1, ws + WS_H2);
  k_dec2<<<8192, 512, 0, stream>>>(dW2, db2, ws + WS_H2, out);
}

// Round 8
// 362.501 us; speedup vs baseline: 1.8106x; 1.8106x over previous
//
#include <hip/hip_runtime.h>

// Native clang vector type — accepted by __builtin_nontemporal_load
typedef float vf4 __attribute__((ext_vector_type(4)));

// Workspace float offsets
#define WS_FPART 0      // fpart[4][128] (k_f partials, one per t; summed in k_h1)
#define WS_H1    640    // h1[450]
#define WS_FEAT  1152   // feat[450]
#define WS_H2    1664   // h2[450]

// K1: fpart[t][i] = sum_{p,c} x[4+t,p,c] * TwE[t,i] * PE[p,i] * CE[c,i]
// 512 blocks = 4 per output i (one per t). Per-block L2-serial read = 128 KB.
__global__ __launch_bounds__(256) void k_f(
    const float* __restrict__ x, const float* __restrict__ TwE,
    const float* __restrict__ PE, const float* __restrict__ CE,
    float* __restrict__ fpart) {
  const int i = blockIdx.x >> 2;
  const int t = blockIdx.x & 3;
  const int tid = threadIdx.x;
  __shared__ float sCE[128];
  __shared__ float coef[256];   // coef[p] = TwE[t,i] * PE[p,i]
  __shared__ float red[4];
  const float tw = TwE[t * 128 + i];     // wave-uniform scalar load
  if (tid < 128) sCE[tid] = CE[tid * 128 + i];
  coef[tid] = tw * PE[tid * 128 + i];
  __syncthreads();
  const int lane = tid & 63;
  const int wv = tid >> 6;
  const float2 ce = ((const float2*)sCE)[lane];
  const float2* Xw = (const float2*)(x + 4 * 256 * 128);  // window start
  float acc = 0.f;
  const int l0 = wv * 64;                // each wave: 64 of this block's 256 p-rows
#pragma unroll 8
  for (int k = 0; k < 64; ++k) {
    int l = l0 + k;                      // p index
    int q = (t << 8) + l;                // global (t,p) row in window
    float2 v = Xw[q * 64 + lane];        // coalesced 512B wave load
    acc += coef[l] * (v.x * ce.x + v.y * ce.y);
  }
#pragma unroll
  for (int off = 32; off > 0; off >>= 1) acc += __shfl_down(acc, off);
  if (lane == 0) red[wv] = acc;
  __syncthreads();
  if (tid == 0) fpart[t * 128 + i] = red[0] + red[1] + red[2] + red[3];
}

// K2+K3 merged: each block sums fpart -> f, redundantly computes feat0 = mE@f
// (thread-per-row, mE 230 KB/block through L1; rows are 512B float4 so this
// stays 8-lines-per-wave-load), then its 4 rows of h1 wave-per-row.
__global__ __launch_bounds__(256) void k_h1(
    const float* __restrict__ fpart, const float* __restrict__ mE,
    const float* __restrict__ eW1, const float* __restrict__ eb1,
    float* __restrict__ h1) {
  __shared__ float sf[128];
  __shared__ float sfeat0[450];
  const int tid = threadIdx.x;
  if (tid < 128)
    sf[tid] = (fpart[tid] + fpart[128 + tid]) + (fpart[256 + tid] + fpart[384 + tid]);
  __syncthreads();
  for (int r = tid; r < 450; r += 256) {
    const float4* row = (const float4*)(mE + r * 128);  // 512B row, 16B-aligned
    float a0 = 0.f, a1 = 0.f, a2 = 0.f, a3 = 0.f;
#pragma unroll 8
    for (int k = 0; k < 32; ++k) {
      float4 m = row[k];
      a0 += m.x * sf[4 * k];      // LDS same-address across lanes: broadcast
      a1 += m.y * sf[4 * k + 1];
      a2 += m.z * sf[4 * k + 2];
      a3 += m.w * sf[4 * k + 3];
    }
    sfeat0[r] = (a0 + a1) + (a2 + a3);
  }
  __syncthreads();
  const int lane = tid & 63;
  const int row = blockIdx.x * 4 + (tid >> 6);
  if (row < 450) {
    const float2* Wr = (const float2*)(eW1 + row * 450);
    float acc = 0.f;
#pragma unroll
    for (int k = 0; k < 4; ++k) {
      int idx = lane + (k << 6);
      if (idx < 225) {
        float2 w = Wr[idx];
        acc += w.x * sfeat0[2 * idx] + w.y * sfeat0[2 * idx + 1];
      }
    }
#pragma unroll
    for (int off = 32; off > 0; off >>= 1) acc += __shfl_down(acc, off);
    if (lane == 0) h1[row] = fmaxf(acc + eb1[row], 0.f);
  }
}

// K4/K5: vout = [relu](W @ vin + b), W is 450x450. Wave per row.
__global__ __launch_bounds__(256) void k_mv450(
    const float* __restrict__ W, const float* __restrict__ b,
    const float* __restrict__ vin, float* __restrict__ vout, int relu) {
  __shared__ float sv[450];
  const int tid = threadIdx.x;
  if (tid < 450) sv[tid] = vin[tid];
  if (tid + 256 < 450) sv[tid + 256] = vin[tid + 256];
  __syncthreads();
  const int lane = tid & 63;
  const int row = blockIdx.x * 4 + (tid >> 6);
  if (row >= 450) return;
  const float2* Wr = (const float2*)(W + row * 450);
  float acc = 0.f;
#pragma unroll
  for (int k = 0; k < 4; ++k) {
    int idx = lane + (k << 6);
    if (idx < 225) {
      float2 w = Wr[idx];
      acc += w.x * sv[2 * idx] + w.y * sv[2 * idx + 1];
    }
  }
#pragma unroll
  for (int off = 32; off > 0; off >>= 1) acc += __shfl_down(acc, off);
  if (lane == 0) {
    float r = acc + b[row];
    if (relu) r = fmaxf(r, 0.f);
    vout[row] = r;
  }
}

// K6 v2: out = dec_W2 @ h2 + dec_b2. PERSISTENT grid: 1024 blocks x 512 thr
// = 8192 waves = exactly 32 waves/CU. Each wave owns 8 CONTIGUOUS row-pairs
// (28.8 KB sequential stream: next-load address page-local, and the next
// pair's loads overlap the current pair's shuffle-reduce — no barrier in the
// loop). sv2 staging amortized 8x vs the 8192-block version. NT loads/stores
// (fills flush the LLC every replay; dec_W2 can never be retained).
#define DEC2_BLOCKS 1024
__global__ __launch_bounds__(512) void k_dec2(
    const float* __restrict__ W, const float* __restrict__ b,
    const float* __restrict__ h, float* __restrict__ out) {
  __shared__ float sv2[900];
  const int tid = threadIdx.x;
  for (int k = tid; k < 900; k += 512) sv2[k] = h[k < 450 ? k : k - 450];
  __syncthreads();
  const int lane = tid & 63;
  const int wv = tid >> 6;
  const int rp0 = (blockIdx.x * 8 + wv) * 8;     // this wave's first row pair
#pragma unroll 2
  for (int it = 0; it < 8; ++it) {
    const int rp = rp0 + it;                     // row pair, 0..65535
    const vf4* Wp = (const vf4*)(W + (size_t)rp * 900);
    float accA = 0.f, accB = 0.f;
#pragma unroll
    for (int k = 0; k < 3; ++k) {
      int j = lane + (k << 6);          // 0..191
      vf4 w = __builtin_nontemporal_load(&Wp[j]);
      const float* s = &sv2[4 * j];
      float p01 = w.x * s[0] + w.y * s[1];
      float p23 = w.z * s[2] + w.w * s[3];
      if (4 * j + 3 < 450)      accA += p01 + p23;   // j <= 111
      else if (4 * j >= 450)    accB += p01 + p23;   // j >= 113
      else { accA += p01; accB += p23; }             // j == 112 straddles
    }
    if (lane < 33) {                    // j = 192..224, all row B
      int j = 192 + lane;
      vf4 w = __builtin_nontemporal_load(&Wp[j]);
      const float* s = &sv2[4 * j];
      accB += w.x * s[0] + w.y * s[1] + w.z * s[2] + w.w * s[3];
    }
#pragma unroll
    for (int off = 32; off > 0; off >>= 1) {
      accA += __shfl_down(accA, off);
      accB += __shfl_down(accB, off);
    }
    if (lane == 0) {
      int r = rp * 2;
      __builtin_nontemporal_store(accA + b[r],     &out[r]);
      __builtin_nontemporal_store(accB + b[r + 1], &out[r + 1]);
    }
  }
}

extern "C" void kernel_launch(void* const* d_in, const int* in_sizes, int n_in,
                              void* d_out, int out_size, void* d_ws, size_t ws_size,
                              hipStream_t stream) {
  const float* x   = (const float*)d_in[0];
  const float* TwE = (const float*)d_in[2];
  const float* PE  = (const float*)d_in[3];
  const float* CE  = (const float*)d_in[4];
  const float* mE  = (const float*)d_in[5];
  const float* eW1 = (const float*)d_in[6];
  const float* eb1 = (const float*)d_in[7];
  const float* eW2 = (const float*)d_in[8];
  const float* eb2 = (const float*)d_in[9];
  const float* dW1 = (const float*)d_in[10];
  const float* db1 = (const float*)d_in[11];
  const float* dW2 = (const float*)d_in[12];
  const float* db2 = (const float*)d_in[13];
  float* out = (float*)d_out;
  float* ws  = (float*)d_ws;

  k_f    <<<512,         256, 0, stream>>>(x, TwE, PE, CE, ws + WS_FPART);
  k_h1   <<<113,         256, 0, stream>>>(ws + WS_FPART, mE, eW1, eb1, ws + WS_H1);
  k_mv450<<<113,         256, 0, stream>>>(eW2, eb2, ws + WS_H1, ws + WS_FEAT, 0);
  k_mv450<<<113,         256, 0, stream>>>(dW1, db1, ws + WS_FEAT, ws + WS_H2, 1);
  k_dec2 <<<DEC2_BLOCKS, 512, 0, stream>>>(dW2, db2, ws + WS_H2, out);
}

// Round 9
// 358.849 us; speedup vs baseline: 1.8291x; 1.0102x over previous
//
#include <hip/hip_runtime.h>

// Native clang vector type — accepted by __builtin_nontemporal_load
typedef float vf4 __attribute__((ext_vector_type(4)));

// Workspace float offsets
#define WS_FPART 0      // fpart[4][128] (k_f partials, one per t; summed in k_h1)
#define WS_H1    640    // h1[450]
#define WS_FEAT  1152   // feat[450]
#define WS_H2    1664   // h2[450]

// K1: fpart[t][i] = sum_{p,c} x[4+t,p,c] * TwE[t,i] * PE[p,i] * CE[c,i]
// 512 blocks = 4 per output i (one per t). Per-block L2-serial read = 128 KB.
__global__ __launch_bounds__(256) void k_f(
    const float* __restrict__ x, const float* __restrict__ TwE,
    const float* __restrict__ PE, const float* __restrict__ CE,
    float* __restrict__ fpart) {
  const int i = blockIdx.x >> 2;
  const int t = blockIdx.x & 3;
  const int tid = threadIdx.x;
  __shared__ float sCE[128];
  __shared__ float coef[256];   // coef[p] = TwE[t,i] * PE[p,i]
  __shared__ float red[4];
  const float tw = TwE[t * 128 + i];     // wave-uniform scalar load
  if (tid < 128) sCE[tid] = CE[tid * 128 + i];
  coef[tid] = tw * PE[tid * 128 + i];
  __syncthreads();
  const int lane = tid & 63;
  const int wv = tid >> 6;
  const float2 ce = ((const float2*)sCE)[lane];
  const float2* Xw = (const float2*)(x + 4 * 256 * 128);  // window start
  float acc = 0.f;
  const int l0 = wv * 64;                // each wave: 64 of this block's 256 p-rows
#pragma unroll 8
  for (int k = 0; k < 64; ++k) {
    int l = l0 + k;                      // p index
    int q = (t << 8) + l;                // global (t,p) row in window
    float2 v = Xw[q * 64 + lane];        // coalesced 512B wave load
    acc += coef[l] * (v.x * ce.x + v.y * ce.y);
  }
#pragma unroll
  for (int off = 32; off > 0; off >>= 1) acc += __shfl_down(acc, off);
  if (lane == 0) red[wv] = acc;
  __syncthreads();
  if (tid == 0) fpart[t * 128 + i] = red[0] + red[1] + red[2] + red[3];
}

// K2+K3 merged: each block sums fpart -> f, redundantly computes feat0 = mE@f
// (thread-per-row, mE 230 KB/block through L1; rows are 512B float4 so this
// stays cache-line-efficient), then its 4 rows of h1 = relu(eW1@feat0 + eb1)
// wave-per-row. NOTE (R5/R7): the 450-row redundant phases must NOT be
// extended to eW1/eW2 — the middle chain is latency-bound and must stay
// distributed across blocks (4 rows/block).
__global__ __launch_bounds__(256) void k_h1(
    const float* __restrict__ fpart, const float* __restrict__ mE,
    const float* __restrict__ eW1, const float* __restrict__ eb1,
    float* __restrict__ h1) {
  __shared__ float sf[128];
  __shared__ float sfeat0[450];
  const int tid = threadIdx.x;
  if (tid < 128)
    sf[tid] = (fpart[tid] + fpart[128 + tid]) + (fpart[256 + tid] + fpart[384 + tid]);
  __syncthreads();
  for (int r = tid; r < 450; r += 256) {
    const float4* row = (const float4*)(mE + r * 128);  // 512B row, 16B-aligned
    float a0 = 0.f, a1 = 0.f, a2 = 0.f, a3 = 0.f;
#pragma unroll 8
    for (int k = 0; k < 32; ++k) {
      float4 m = row[k];
      a0 += m.x * sf[4 * k];      // LDS same-address across lanes: broadcast
      a1 += m.y * sf[4 * k + 1];
      a2 += m.z * sf[4 * k + 2];
      a3 += m.w * sf[4 * k + 3];
    }
    sfeat0[r] = (a0 + a1) + (a2 + a3);
  }
  __syncthreads();
  const int lane = tid & 63;
  const int row = blockIdx.x * 4 + (tid >> 6);
  if (row < 450) {
    const float2* Wr = (const float2*)(eW1 + row * 450);
    float acc = 0.f;
#pragma unroll
    for (int k = 0; k < 4; ++k) {
      int idx = lane + (k << 6);
      if (idx < 225) {
        float2 w = Wr[idx];
        acc += w.x * sfeat0[2 * idx] + w.y * sfeat0[2 * idx + 1];
      }
    }
#pragma unroll
    for (int off = 32; off > 0; off >>= 1) acc += __shfl_down(acc, off);
    if (lane == 0) h1[row] = fmaxf(acc + eb1[row], 0.f);
  }
}

// K4/K5: vout = [relu](W @ vin + b), W is 450x450. Wave per row.
__global__ __launch_bounds__(256) void k_mv450(
    const float* __restrict__ W, const float* __restrict__ b,
    const float* __restrict__ vin, float* __restrict__ vout, int relu) {
  __shared__ float sv[450];
  const int tid = threadIdx.x;
  if (tid < 450) sv[tid] = vin[tid];
  if (tid + 256 < 450) sv[tid + 256] = vin[tid + 256];
  __syncthreads();
  const int lane = tid & 63;
  const int row = blockIdx.x * 4 + (tid >> 6);
  if (row >= 450) return;
  const float2* Wr = (const float2*)(W + row * 450);
  float acc = 0.f;
#pragma unroll
  for (int k = 0; k < 4; ++k) {
    int idx = lane + (k << 6);
    if (idx < 225) {
      float2 w = Wr[idx];
      acc += w.x * sv[2 * idx] + w.y * sv[2 * idx + 1];
    }
  }
#pragma unroll
  for (int off = 32; off > 0; off >>= 1) acc += __shfl_down(acc, off);
  if (lane == 0) {
    float r = acc + b[row];
    if (relu) r = fmaxf(r, 0.f);
    vout[row] = r;
  }
}

// K6: out = dec_W2 @ h2 + dec_b2. Wave per ROW-PAIR (225 float4, 16B-aligned:
// pair stride 3600B). NT loads/stores (the 900-MiB poison fills flush the LLC
// every replay, so dec_W2 can never be retained — stream it). 512-thread
// blocks (8 pairs/block) halve the CP block-dispatch ramp vs 16384 blocks.
// R8 note: persistent 1024-block variant with 8 contiguous pairs/wave was
// neutral — ramp and staging amortization are not real costs here.
__global__ __launch_bounds__(512) void k_dec2(
    const float* __restrict__ W, const float* __restrict__ b,
    const float* __restrict__ h, float* __restrict__ out) {
  __shared__ float sv2[900];
  const int tid = threadIdx.x;
  for (int k = tid; k < 900; k += 512) sv2[k] = h[k < 450 ? k : k - 450];
  __syncthreads();
  const int lane = tid & 63;
  const int rp = blockIdx.x * 8 + (tid >> 6);    // row pair, 0..65535
  const vf4* Wp = (const vf4*)(W + (size_t)rp * 900);
  float accA = 0.f, accB = 0.f;
#pragma unroll
  for (int k = 0; k < 3; ++k) {
    int j = lane + (k << 6);          // 0..191
    vf4 w = __builtin_nontemporal_load(&Wp[j]);
    const float* s = &sv2[4 * j];
    float p01 = w.x * s[0] + w.y * s[1];
    float p23 = w.z * s[2] + w.w * s[3];
    if (4 * j + 3 < 450)      accA += p01 + p23;   // j <= 111
    else if (4 * j >= 450)    accB += p01 + p23;   // j >= 113
    else { accA += p01; accB += p23; }             // j == 112 straddles
  }
  if (lane < 33) {                    // j = 192..224, all row B
    int j = 192 + lane;
    vf4 w = __builtin_nontemporal_load(&Wp[j]);
    const float* s = &sv2[4 * j];
    accB += w.x * s[0] + w.y * s[1] + w.z * s[2] + w.w * s[3];
  }
#pragma unroll
  for (int off = 32; off > 0; off >>= 1) {
    accA += __shfl_down(accA, off);
    accB += __shfl_down(accB, off);
  }
  if (lane == 0) {
    int r = rp * 2;
    __builtin_nontemporal_store(accA + b[r],     &out[r]);
    __builtin_nontemporal_store(accB + b[r + 1], &out[r + 1]);
  }
}

extern "C" void kernel_launch(void* const* d_in, const int* in_sizes, int n_in,
                              void* d_out, int out_size, void* d_ws, size_t ws_size,
                              hipStream_t stream) {
  const float* x   = (const float*)d_in[0];
  const float* TwE = (const float*)d_in[2];
  const float* PE  = (const float*)d_in[3];
  const float* CE  = (const float*)d_in[4];
  const float* mE  = (const float*)d_in[5];
  const float* eW1 = (const float*)d_in[6];
  const float* eb1 = (const float*)d_in[7];
  const float* eW2 = (const float*)d_in[8];
  const float* eb2 = (const float*)d_in[9];
  const float* dW1 = (const float*)d_in[10];
  const float* db1 = (const float*)d_in[11];
  const float* dW2 = (const float*)d_in[12];
  const float* db2 = (const float*)d_in[13];
  float* out = (float*)d_out;
  float* ws  = (float*)d_ws;

  k_f    <<<512,  256, 0, stream>>>(x, TwE, PE, CE, ws + WS_FPART);
  k_h1   <<<113,  256, 0, stream>>>(ws + WS_FPART, mE, eW1, eb1, ws + WS_H1);
  k_mv450<<<113,  256, 0, stream>>>(eW2, eb2, ws + WS_H1, ws + WS_FEAT, 0);
  k_mv450<<<113,  256, 0, stream>>>(dW1, db1, ws + WS_FEAT, ws + WS_H2, 1);
  k_dec2 <<<8192, 512, 0, stream>>>(dW2, db2, ws + WS_H2, out);
}